// Round 11
// baseline (201.937 us; speedup 1.0000x reference)
//
#include <hip/hip_runtime.h>
#include <hip/hip_fp16.h>
#include <math.h>

#define DD 256
static constexpr int N_MET  = 2534;
static constexpr int N_RXN  = 4881;
static constexpr int N_GENE = 6607;
static constexpr int NE     = 262144;
static constexpr int NP     = 131072;

static constexpr int NCHUNK = 256;       // NE / 1024
static constexpr int NCHG   = 128;       // NP / 1024
static constexpr int NBE    = 77;        // edge buckets of 64
static constexpr int NBN    = 80;        // node buckets of 32
static constexpr int NBG    = 104;       // gene buckets of 64
static constexpr int CHS    = 80;        // chE/chN stride
static constexpr int NCOL   = NBE + NBN + NBG;          // 261 scan columns
static constexpr int GEMM_BLOCKS = (N_MET + 15) / 16;   // 159
static constexpr int KP2_GEMM0 = NBE + NBN + NBG;       // 261

static constexpr float SCL  = 2048.f;    // fp16 storage scale (linear pipeline)
static constexpr float SCLI = 1.f / 2048.f;

// ---------- wave reductions / broadcasts (64 lanes) ----------
__device__ __forceinline__ float waveSum(float v) {
  #pragma unroll
  for (int o = 32; o > 0; o >>= 1) v += __shfl_xor(v, o, 64);
  return v;
}
__device__ __forceinline__ float waveMax(float v) {
  #pragma unroll
  for (int o = 32; o > 0; o >>= 1) v = fmaxf(v, __shfl_xor(v, o, 64));
  return v;
}
__device__ __forceinline__ int   bcasti(int v, int l)   { return __builtin_amdgcn_readlane(v, l); }
__device__ __forceinline__ float bcastf(float v, int l) {
  return __int_as_float(__builtin_amdgcn_readlane(__float_as_int(v), l));
}

// ---------- fp16 pack/unpack ----------
__device__ __forceinline__ float4 h4f(uint2 u) {
  __half2 a = *reinterpret_cast<__half2*>(&u.x);
  __half2 b = *reinterpret_cast<__half2*>(&u.y);
  float2 fa = __half22float2(a), fb = __half22float2(b);
  return make_float4(fa.x, fa.y, fb.x, fb.y);
}
__device__ __forceinline__ unsigned f2h2(float a, float b) {
  __half2 h = __floats2half2_rn(a, b);
  return *reinterpret_cast<unsigned*>(&h);
}

// ---------- KH: vedot (blk 0..31) + LDS bucket hists + cntR (blk 32..287) ----------
__global__ __launch_bounds__(1024) void KH_k(
    const int* __restrict__ he_node, const int* __restrict__ he_edge,
    const int* __restrict__ rtg_rxn, const int* __restrict__ rtg_gene,
    int* cntR,
    int* __restrict__ chE, int* __restrict__ chN, int* __restrict__ chG,
    const float* __restrict__ We0, const float* __restrict__ att0,
    const float* __restrict__ We1, const float* __restrict__ att1,
    float* __restrict__ ve0, float* __restrict__ ve1) {
  int blk = blockIdx.x, tid = threadIdx.x;
  if (blk < 32) {
    int wid = blk * 16 + (tid >> 6);   // 0..511
    int lane = tid & 63;
    const float* We = (wid < 256) ? We0 : We1;
    const float* at = (wid < 256) ? att0 : att1;
    int r = wid & 255;
    float4 a = ((const float4*)(We + (size_t)r * DD))[lane];
    float4 v = ((const float4*)(at + DD))[lane];
    float s = waveSum(a.x * v.x + a.y * v.y + a.z * v.z + a.w * v.w);
    if (lane == 0) ((wid < 256) ? ve0 : ve1)[r] = s;
    return;
  }
  int c = blk - 32;                     // chunk id, 0..255
  __shared__ int hE[NBE], hN[NBN], hG[NBG];
  if (tid < NBE) hE[tid] = 0;
  if (tid >= 128 && tid < 128 + NBN) hN[tid - 128] = 0;
  if (tid >= 256 && tid < 256 + NBG) hG[tid - 256] = 0;
  __syncthreads();
  int i = c * 1024 + tid;               // i < NE always
  int n = he_node[i], e = he_edge[i];
  atomicAdd(&hE[e >> 6], 1); atomicAdd(&hN[n >> 5], 1);
  if (c < NCHG) {
    int r = rtg_rxn[i], g = rtg_gene[i];
    atomicAdd(&cntR[r], 1);
    atomicAdd(&hG[g >> 6], 1);
  }
  __syncthreads();
  if (tid < NBE) chE[c * CHS + tid] = hE[tid];
  if (tid >= 128 && tid < 128 + NBN) chN[c * CHS + (tid - 128)] = hN[tid - 128];
  if (c < NCHG && tid >= 256 && tid < 256 + NBG) chG[c * NBG + (tid - 256)] = hG[tid - 256];
}

// ---------- KScan: column scans (blk 0..16, emit bucket totals) + gdot ----------
__global__ __launch_bounds__(1024) void KScan_k(
    int* __restrict__ chE, int* __restrict__ chN, int* __restrict__ chG,
    int* __restrict__ totE, int* __restrict__ totN, int* __restrict__ totG,
    const float* __restrict__ gene_x,
    const float* __restrict__ ve0, const float* __restrict__ ve1,
    float* __restrict__ gdot0, float* __restrict__ gdot1) {
  int blk = blockIdx.x, tid = threadIdx.x;
  if (blk < 17) {
    int colw = blk * 16 + (tid >> 6);
    int lane = tid & 63;
    if (colw >= NCOL) return;
    if (colw < NBE + NBN) {
      int side = colw >= NBE;
      int b = colw - side * NBE;
      int* ch = side ? chN : chE;
      int* tot = side ? totN : totE;
      int v[4]; int s = 0;
      int cbase = lane * 4;
      #pragma unroll
      for (int k = 0; k < 4; ++k) { v[k] = ch[(cbase + k) * CHS + b]; s += v[k]; }
      int inc = s;
      #pragma unroll
      for (int o = 1; o < 64; o <<= 1) { int t = __shfl_up(inc, o, 64); if (lane >= o) inc += t; }
      if (lane == 63) tot[b] = inc;
      int ex = inc - s;
      #pragma unroll
      for (int k = 0; k < 4; ++k) { int t = v[k]; ch[(cbase + k) * CHS + b] = ex; ex += t; }
    } else {
      int b = colw - NBE - NBN;
      int v[2]; int s = 0;
      int cbase = lane * 2;
      #pragma unroll
      for (int k = 0; k < 2; ++k) { v[k] = chG[(cbase + k) * NBG + b]; s += v[k]; }
      int inc = s;
      #pragma unroll
      for (int o = 1; o < 64; o <<= 1) { int t = __shfl_up(inc, o, 64); if (lane >= o) inc += t; }
      if (lane == 63) totG[b] = inc;
      int ex = inc - s;
      #pragma unroll
      for (int k = 0; k < 2; ++k) { int t = v[k]; chG[(cbase + k) * NBG + b] = ex; ex += t; }
    }
    return;
  }
  // gdot
  int wid = (blk - 17) * 16 + (tid >> 6);
  int lane = tid & 63;
  if (wid >= N_GENE) return;
  float4 a  = ((const float4*)gene_x)[(size_t)wid * 64 + lane];
  float4 v0 = ((const float4*)ve0)[lane];
  float4 v1 = ((const float4*)ve1)[lane];
  float s0 = waveSum(a.x * v0.x + a.y * v0.y + a.z * v0.z + a.w * v0.w);
  float s1 = waveSum(a.x * v1.x + a.y * v1.y + a.z * v1.z + a.w * v1.w);
  if (lane == 0) { gdot0[wid] = s0; gdot1[wid] = s1; }
}

// in-place 128-entry LDS inclusive scan
__device__ __forceinline__ void ldsScan128(int* sc, int tid) {
  #pragma unroll
  for (int o = 1; o < 128; o <<= 1) {
    int t = (tid < 128 && tid >= o) ? sc[tid - o] : 0;
    __syncthreads();
    if (tid < 128) sc[tid] += t;
    __syncthreads();
  }
}

// ---------- KP1: bucket partition (packed 8B/4B records) + se atomics ----------
__global__ __launch_bounds__(1024) void KP1_k(
    const int* __restrict__ he_node, const int* __restrict__ he_edge,
    const float* __restrict__ stoich,
    const int* __restrict__ chE, const int* __restrict__ chN,
    const int* __restrict__ chG,
    const int* __restrict__ totE, const int* __restrict__ totN,
    const int* __restrict__ totG,
    int2* __restrict__ scrE, int2* __restrict__ scrN, int* __restrict__ scrG,
    const int* __restrict__ rtg_rxn, const int* __restrict__ rtg_gene,
    const float* __restrict__ gdot0, const float* __restrict__ gdot1,
    float* __restrict__ seAcc0, float* __restrict__ seAcc1) {
  int c = blockIdx.x, tid = threadIdx.x;
  __shared__ int sc[128];
  __shared__ int cursE[NBE], cursN[NBN], cursG[NBG];
  int v;
  if (tid < 128) sc[tid] = (tid < NBE) ? totE[tid] : 0;
  if (tid < 128) v = sc[tid];
  __syncthreads();
  ldsScan128(sc, tid);
  if (tid < NBE) cursE[tid] = (sc[tid] - v) + chE[c * CHS + tid];
  __syncthreads();
  if (tid < 128) sc[tid] = (tid < NBN) ? totN[tid] : 0;
  if (tid < 128) v = sc[tid];
  __syncthreads();
  ldsScan128(sc, tid);
  if (tid < NBN) cursN[tid] = (sc[tid] - v) + chN[c * CHS + tid];
  __syncthreads();
  if (c < NCHG) {
    if (tid < 128) sc[tid] = (tid < NBG) ? totG[tid] : 0;
    if (tid < 128) v = sc[tid];
    __syncthreads();
    ldsScan128(sc, tid);
    if (tid < NBG) cursG[tid] = (sc[tid] - v) + chG[c * NBG + tid];
  }
  __syncthreads();
  int i = c * 1024 + tid;
  int n = he_node[i], e = he_edge[i];
  int st = __float_as_int(stoich[i]);
  int dE = atomicAdd(&cursE[e >> 6], 1);
  scrE[dE] = make_int2((e << 12) | n, st);
  int dN = atomicAdd(&cursN[n >> 5], 1);
  scrN[dN] = make_int2((n << 13) | e, st);
  if (c < NCHG) {
    int r = rtg_rxn[i], g = rtg_gene[i];
    int dG = atomicAdd(&cursG[g >> 6], 1);
    scrG[dG] = (g << 13) | r;
    atomicAdd(&seAcc0[r], gdot0[g]);
    atomicAdd(&seAcc1[r], gdot1[g]);
  }
}

// ---------- GEMM body: Y(half,scaled) = X @ W; optional renorm; fused sn(f32) ----------
template <bool RENORM, bool XH>
__device__ __forceinline__ void gemm_body(const void* __restrict__ Xv,
                                          const float* __restrict__ W,
                                          const float* __restrict__ att,
                                          __half* __restrict__ Y,
                                          float* __restrict__ sn, int M, int r0) {
  __shared__ float Xs[256][20];
  __shared__ float red[4][16];
  __shared__ float scl[16];
  int tid = threadIdx.x;
  int w = tid >> 6, lane = tid & 63;
  float xv[16];
  #pragma unroll
  for (int i = 0; i < 16; ++i) {
    int r = r0 + i;
    if (r < M) {
      if (XH) xv[i] = __half2float(((const __half*)Xv)[(size_t)r * DD + tid]);
      else    xv[i] = ((const float*)Xv)[(size_t)r * DD + tid];
    } else xv[i] = 0.f;
  }
  if (RENORM) {
    #pragma unroll
    for (int i = 0; i < 16; ++i) {
      float v = waveSum(xv[i] * xv[i]);
      if (lane == 0) red[w][i] = v;
    }
    __syncthreads();
    if (tid < 16) {
      float t = red[0][tid] + red[1][tid] + red[2][tid] + red[3][tid];
      scl[tid] = fminf(1.f, 1.f / (sqrtf(t) + 1e-12f));
    }
    __syncthreads();
    #pragma unroll
    for (int i = 0; i < 16; ++i) xv[i] *= scl[i];
  }
  #pragma unroll
  for (int i = 0; i < 16; ++i) Xs[tid][i] = xv[i];
  __syncthreads();
  float acc[16];
  #pragma unroll
  for (int i = 0; i < 16; ++i) acc[i] = 0.f;
  const float* wp = W + tid;
  #pragma unroll 8
  for (int k = 0; k < 256; ++k) {
    float wv = wp[(size_t)k * DD];
    const float4* xr = reinterpret_cast<const float4*>(&Xs[k][0]);
    float4 a0 = xr[0], a1 = xr[1], a2 = xr[2], a3 = xr[3];
    acc[0]  += a0.x * wv; acc[1]  += a0.y * wv; acc[2]  += a0.z * wv; acc[3]  += a0.w * wv;
    acc[4]  += a1.x * wv; acc[5]  += a1.y * wv; acc[6]  += a1.z * wv; acc[7]  += a1.w * wv;
    acc[8]  += a2.x * wv; acc[9]  += a2.y * wv; acc[10] += a2.z * wv; acc[11] += a2.w * wv;
    acc[12] += a3.x * wv; acc[13] += a3.y * wv; acc[14] += a3.z * wv; acc[15] += a3.w * wv;
  }
  const float ysc = XH ? 1.f : SCL;
  #pragma unroll
  for (int i = 0; i < 16; ++i) {
    int r = r0 + i;
    if (r < M) Y[(size_t)r * DD + tid] = __float2half_rn(acc[i] * ysc);
  }
  float av = att[tid];
  __syncthreads();
  #pragma unroll
  for (int i = 0; i < 16; ++i) {
    float v = waveSum(acc[i] * av);
    if (lane == 0) red[w][i] = v;
  }
  __syncthreads();
  if (tid < 16) {
    int r = r0 + tid;
    if (r < M) sn[r] = (red[0][tid] + red[1][tid] + red[2][tid] + red[3][tid])
                       * (XH ? SCLI : 1.f);
  }
}

// block-sum over 256 threads (int)
__device__ __forceinline__ int blockSumInt256(int v) {
  __shared__ int s4[4];
  #pragma unroll
  for (int o = 32; o > 0; o >>= 1) v += __shfl_xor(v, o, 64);
  if ((threadIdx.x & 63) == 0) s4[threadIdx.x >> 6] = v;
  __syncthreads();
  return s4[0] + s4[1] + s4[2] + s4[3];
}

// ---------- KP2: in-bucket count+scan → offs + CSR placement + gemm0 ----------
__global__ __launch_bounds__(256) void KP2_k(
    const int* __restrict__ totE, const int* __restrict__ totN,
    const int* __restrict__ totG,
    const int2* __restrict__ scrE, const int2* __restrict__ scrN,
    const int* __restrict__ scrG,
    int* __restrict__ offsE, int* __restrict__ offsN, int* __restrict__ offsG,
    int2* __restrict__ payE, int2* __restrict__ payN, int* __restrict__ rxnG,
    const float* __restrict__ emb, const float* __restrict__ W0,
    const float* __restrict__ att0, __half* __restrict__ xp,
    float* __restrict__ sn) {
  int blk = blockIdx.x, tid = threadIdx.x;
  if (blk >= KP2_GEMM0) {
    gemm_body<true, false>(emb, W0, att0, xp, sn, N_MET, (blk - KP2_GEMM0) * 16);
    return;
  }
  __shared__ int cnt[64];
  __shared__ int curs[64];
  int side, b, klo, kcnt, nk, btot;
  const int* tot;
  if (blk < NBE)            { side = 0; b = blk;             tot = totE; klo = 64 * b; nk = N_RXN;  kcnt = min(64, N_RXN  - klo); }
  else if (blk < NBE + NBN) { side = 1; b = blk - NBE;       tot = totN; klo = 32 * b; nk = N_MET;  kcnt = min(32, N_MET  - klo); }
  else                      { side = 2; b = blk - NBE - NBN; tot = totG; klo = 64 * b; nk = N_GENE; kcnt = min(64, N_GENE - klo); }
  btot = tot[b];
  int pv = (tid < b) ? tot[tid] : 0;
  int base = blockSumInt256(pv);
  if (tid < 64) cnt[tid] = 0;
  __syncthreads();
  int lo = base, hi = base + btot;
  for (int j = lo + tid; j < hi; j += 256) {
    int key;
    if (side == 0)      key = (scrE[j].x >> 12) - klo;
    else if (side == 1) key = (scrN[j].x >> 13) - klo;
    else                key = (scrG[j]   >> 13) - klo;
    atomicAdd(&cnt[key], 1);
  }
  __syncthreads();
  if (tid < 64) {
    int v = cnt[tid];
    int inc = v;
    #pragma unroll
    for (int o = 1; o < 64; o <<= 1) { int t = __shfl_up(inc, o, 64); if (tid >= o) inc += t; }
    int ex = inc - v;
    curs[tid] = base + ex;
    int* offs = (side == 0) ? offsE : (side == 1) ? offsN : offsG;
    if (tid < kcnt) offs[klo + tid] = base + ex;
    if (tid == 0 && klo + kcnt == nk) offs[nk] = base + btot;
  }
  __syncthreads();
  for (int j = lo + tid; j < hi; j += 256) {
    if (side == 0) {
      int2 r = scrE[j];
      int e = r.x >> 12, n = r.x & 4095;
      int slot = atomicAdd(&curs[e - klo], 1);
      payE[slot] = make_int2(n, r.y);
    } else if (side == 1) {
      int2 r = scrN[j];
      int n = r.x >> 13, e = r.x & 8191;
      int slot = atomicAdd(&curs[n - klo], 1);
      payN[slot] = make_int2(e, r.y);
    } else {
      int pw = scrG[j];
      int g = pw >> 13, rr = pw & 8191;
      int slot = atomicAdd(&curs[g - klo], 1);
      rxnG[slot] = rr;
    }
  }
}

// standalone gemm (layer 1): X = cur (half, scaled)
__global__ __launch_bounds__(256) void gemm1_k(const __half* __restrict__ X,
                                               const float* __restrict__ W,
                                               const float* __restrict__ att,
                                               __half* __restrict__ Y,
                                               float* __restrict__ sn, int M) {
  gemm_body<false, true>(X, W, att, Y, sn, M, blockIdx.x * 16);
}

// ---------- paired-row gather: one uint4/lane covers TWO fp16 rows per batch-step ----
// half = lane>>5 (0: even batch rows, 1: odd), fl = lane&31 (8-feature slice).
// After the xor(32) combine, all lanes hold the full per-slice sum.
__device__ __forceinline__ void gatherPair(float (&acc)[8], const uint4* __restrict__ src,
                                           const int (&rv)[4], const float (&wv)[4],
                                           int nc, int half, int fl) {
  #pragma unroll
  for (int c = 0; c < 4; ++c) {
    int lim = nc - c * 64; if (lim > 64) lim = 64;
    for (int t = 0; t < lim; t += 16) {
      uint4 a[8]; float w[8];
      #pragma unroll
      for (int q = 0; q < 8; ++q) {
        int   n0 = bcasti(rv[c], t + 2 * q);
        int   n1 = bcasti(rv[c], t + 2 * q + 1);
        float w0 = bcastf(wv[c], t + 2 * q);
        float w1 = bcastf(wv[c], t + 2 * q + 1);
        int n = half ? n1 : n0;
        w[q]  = half ? w1 : w0;
        a[q]  = src[(size_t)n * 32 + fl];
      }
      #pragma unroll
      for (int q = 0; q < 8; ++q) {
        float4 lo = h4f(make_uint2(a[q].x, a[q].y));
        float4 hi = h4f(make_uint2(a[q].z, a[q].w));
        acc[0] += w[q] * lo.x; acc[1] += w[q] * lo.y;
        acc[2] += w[q] * lo.z; acc[3] += w[q] * lo.w;
        acc[4] += w[q] * hi.x; acc[5] += w[q] * hi.y;
        acc[6] += w[q] * hi.z; acc[7] += w[q] * hi.w;
      }
    }
  }
  #pragma unroll
  for (int k = 0; k < 8; ++k) acc[k] += __shfl_xor(acc[k], 32, 64);
}

__device__ __forceinline__ uint4 pack8h(const float (&a)[8], float s) {
  uint4 u;
  u.x = f2h2(a[0] * s, a[1] * s);
  u.y = f2h2(a[2] * s, a[3] * s);
  u.z = f2h2(a[4] * s, a[5] * s);
  u.w = f2h2(a[6] * s, a[7] * s);
  return u;
}

// ---------- segment mean (wave per segment), fp16 rows, paired gather ----------
template <int STRIDE, bool F32OUT>
__global__ __launch_bounds__(256) void seg_mean_k(const int* __restrict__ offs,
                                                  const int* __restrict__ pay,
                                                  const uint4* __restrict__ src,
                                                  void* __restrict__ dst, int nseg) {
  int wid = (blockIdx.x * 256 + threadIdx.x) >> 6;
  int lane = threadIdx.x & 63;
  int half = lane >> 5, fl = lane & 31;
  if (wid >= nseg) return;
  int beg = offs[wid], end = offs[wid + 1];
  int cnt = end - beg;
  int nc = cnt < 256 ? cnt : 256;
  int rv[4]; float wv[4];
  #pragma unroll
  for (int c = 0; c < 4; ++c) {
    int j = c * 64 + lane;
    if (j < nc) { rv[c] = pay[(size_t)(beg + j) * STRIDE]; wv[c] = 1.f; }
    else        { rv[c] = 0;                               wv[c] = 0.f; }
  }
  float acc[8] = {0.f, 0.f, 0.f, 0.f, 0.f, 0.f, 0.f, 0.f};
  gatherPair(acc, src, rv, wv, nc, half, fl);
  for (int j = 256; j < cnt; ++j) {        // overflow (cold, dead for this data)
    if (half == 0) {
      int n = pay[(size_t)(beg + j) * STRIDE];
      uint4 a = src[(size_t)n * 32 + fl];
      float4 lo = h4f(make_uint2(a.x, a.y)), hi = h4f(make_uint2(a.z, a.w));
      acc[0] += lo.x; acc[1] += lo.y; acc[2] += lo.z; acc[3] += lo.w;
      acc[4] += hi.x; acc[5] += hi.y; acc[6] += hi.z; acc[7] += hi.w;
    }
  }
  float inv = 1.f / (float)(cnt > 1 ? cnt : 1);
  if (half != 0) return;
  if (F32OUT) {
    float s = inv * SCLI;
    float4 o0 = make_float4(acc[0] * s, acc[1] * s, acc[2] * s, acc[3] * s);
    float4 o1 = make_float4(acc[4] * s, acc[5] * s, acc[6] * s, acc[7] * s);
    ((float4*)dst)[(size_t)wid * 64 + fl * 2]     = o0;
    ((float4*)dst)[(size_t)wid * 64 + fl * 2 + 1] = o1;
  } else {
    ((uint4*)dst)[(size_t)wid * 32 + fl] = pack8h(acc, inv);
  }
}

// ---------- me: wave per reaction; softmax (f32) + paired fp16 gather ----------
__global__ __launch_bounds__(256) void me_k(const int* __restrict__ offs,
                                            const int2* __restrict__ payE,
                                            const float* __restrict__ sn,
                                            const float* __restrict__ seAcc,
                                            const int* __restrict__ cntR,
                                            const uint4* __restrict__ xp,
                                            uint4* __restrict__ me,
                                            float4* __restrict__ rstat) {
  int wid = (blockIdx.x * 256 + threadIdx.x) >> 6;
  int lane = threadIdx.x & 63;
  int half = lane >> 5, fl = lane & 31;
  if (wid >= N_RXN) return;
  int rc = cntR[wid];
  float ser = seAcc[wid] / (float)(rc > 1 ? rc : 1);

  int beg = offs[wid], end = offs[wid + 1];
  int cnt = end - beg;
  int nc = cnt < 256 ? cnt : 256;
  int nv[4]; float wv[4]; float stv[4];
  float lmax = -1e30f;
  #pragma unroll
  for (int c = 0; c < 4; ++c) {
    int j = c * 64 + lane;
    if (j < nc) {
      int2 p = payE[beg + j];
      float l = sn[p.x] + ser;
      l = (l >= 0.f) ? l : 0.2f * l;
      nv[c] = p.x; wv[c] = l; stv[c] = __int_as_float(p.y);
      lmax = fmaxf(lmax, l);
    } else { nv[c] = 0; wv[c] = -1e30f; stv[c] = 0.f; }
  }
  for (int j = 256 + lane; j < cnt; j += 64) {
    int2 p = payE[beg + j];
    float l = sn[p.x] + ser;
    l = (l >= 0.f) ? l : 0.2f * l;
    lmax = fmaxf(lmax, l);
  }
  float m = waveMax(lmax);
  float s = 0.f;
  #pragma unroll
  for (int c = 0; c < 4; ++c) {
    if (c * 64 + lane < nc) { float e = expf(wv[c] - m); wv[c] = e; s += e; }
    else wv[c] = 0.f;
  }
  for (int j = 256 + lane; j < cnt; j += 64) {
    int2 p = payE[beg + j];
    float l = sn[p.x] + ser;
    l = (l >= 0.f) ? l : 0.2f * l;
    s += expf(l - m);
  }
  s = waveSum(s);
  float invS = 1.f / (s + 1e-16f);
  #pragma unroll
  for (int c = 0; c < 4; ++c) {
    if (c * 64 + lane < nc) wv[c] = stv[c] * wv[c] * invS;
  }
  if (lane == 0) rstat[wid] = make_float4(ser, m, invS, 0.f);
  float acc[8] = {0.f, 0.f, 0.f, 0.f, 0.f, 0.f, 0.f, 0.f};
  gatherPair(acc, xp, nv, wv, nc, half, fl);
  for (int j = 256; j < cnt; ++j) {        // overflow (cold)
    if (half == 0) {
      int2 p = payE[beg + j];
      float l = sn[p.x] + ser;
      l = (l >= 0.f) ? l : 0.2f * l;
      float w = __int_as_float(p.y) * expf(l - m) * invS;
      uint4 a = xp[(size_t)p.x * 32 + fl];
      float4 lo = h4f(make_uint2(a.x, a.y)), hi = h4f(make_uint2(a.z, a.w));
      acc[0] += w * lo.x; acc[1] += w * lo.y; acc[2] += w * lo.z; acc[3] += w * lo.w;
      acc[4] += w * hi.x; acc[5] += w * hi.y; acc[6] += w * hi.z; acc[7] += w * hi.w;
    }
  }
  if (half != 0) return;
  float invB = 1.f / (float)(cnt > 1 ? cnt : 1);
  me[(size_t)wid * 32 + fl] = pack8h(acc, invB);   // stays scaled by SCL
}

// ---------- out: wave per metabolite; paired gather + tanh (+ skip + LN) ----------
template <bool LN>
__global__ __launch_bounds__(256) void out_k(const int* __restrict__ offs,
                                             const int2* __restrict__ payN,
                                             const float* __restrict__ sn,
                                             const float4* __restrict__ rstat,
                                             const uint4* __restrict__ me,
                                             const float* __restrict__ bias,
                                             const float* __restrict__ ln_g,
                                             const float* __restrict__ ln_b,
                                             uint4* __restrict__ cur) {
  int wid = (blockIdx.x * 256 + threadIdx.x) >> 6;
  int lane = threadIdx.x & 63;
  int half = lane >> 5, fl = lane & 31;
  if (wid >= N_MET) return;
  int beg = offs[wid], end = offs[wid + 1];
  int cnt = end - beg;
  int nc = cnt < 256 ? cnt : 256;
  float sn_n = sn[wid];
  int rv[4]; float wv[4];
  #pragma unroll
  for (int c = 0; c < 4; ++c) {
    int j = c * 64 + lane;
    if (j < nc) {
      int2 p = payN[beg + j];
      float4 st = rstat[p.x];
      float l = sn_n + st.x;
      l = (l >= 0.f) ? l : 0.2f * l;
      rv[c] = p.x;
      wv[c] = __int_as_float(p.y) * expf(l - st.y) * st.z;
    } else { rv[c] = 0; wv[c] = 0.f; }
  }
  float acc[8] = {0.f, 0.f, 0.f, 0.f, 0.f, 0.f, 0.f, 0.f};
  gatherPair(acc, me, rv, wv, nc, half, fl);
  for (int j = 256; j < cnt; ++j) {        // overflow (cold)
    if (half == 0) {
      int2 p = payN[beg + j];
      float4 st = rstat[p.x];
      float l = sn_n + st.x;
      l = (l >= 0.f) ? l : 0.2f * l;
      float w = __int_as_float(p.y) * expf(l - st.y) * st.z;
      uint4 a = me[(size_t)p.x * 32 + fl];
      float4 lo = h4f(make_uint2(a.x, a.y)), hi = h4f(make_uint2(a.z, a.w));
      acc[0] += w * lo.x; acc[1] += w * lo.y; acc[2] += w * lo.z; acc[3] += w * lo.w;
      acc[4] += w * hi.x; acc[5] += w * hi.y; acc[6] += w * hi.z; acc[7] += w * hi.w;
    }
  }
  float invD = SCLI / (float)(cnt > 1 ? cnt : 1);   // unscale + mean
  float4 b0 = ((const float4*)bias)[fl * 2];
  float4 b1 = ((const float4*)bias)[fl * 2 + 1];
  float o[8];
  o[0] = tanhf(acc[0] * invD + b0.x); o[1] = tanhf(acc[1] * invD + b0.y);
  o[2] = tanhf(acc[2] * invD + b0.z); o[3] = tanhf(acc[3] * invD + b0.w);
  o[4] = tanhf(acc[4] * invD + b1.x); o[5] = tanhf(acc[5] * invD + b1.y);
  o[6] = tanhf(acc[6] * invD + b1.z); o[7] = tanhf(acc[7] * invD + b1.w);
  if (!LN) {
    if (half == 0) {
      float so[8];
      #pragma unroll
      for (int k = 0; k < 8; ++k) so[k] = o[k];
      cur[(size_t)wid * 32 + fl] = pack8h(so, SCL);
    }
    return;
  }
  // skip + layernorm over the full 256-feature row
  uint4 pc = cur[(size_t)wid * 32 + fl];
  float4 plo = h4f(make_uint2(pc.x, pc.y)), phi = h4f(make_uint2(pc.z, pc.w));
  float z[8];
  z[0] = o[0] + plo.x * SCLI; z[1] = o[1] + plo.y * SCLI;
  z[2] = o[2] + plo.z * SCLI; z[3] = o[3] + plo.w * SCLI;
  z[4] = o[4] + phi.x * SCLI; z[5] = o[5] + phi.y * SCLI;
  z[6] = o[6] + phi.z * SCLI; z[7] = o[7] + phi.w * SCLI;
  float ls = 0.f;
  #pragma unroll
  for (int k = 0; k < 8; ++k) ls += z[k];
  float mu = waveSum(half == 0 ? ls : 0.f) * (1.f / 256.f);
  float lv = 0.f;
  #pragma unroll
  for (int k = 0; k < 8; ++k) { float d = z[k] - mu; lv += d * d; }
  float var = waveSum(half == 0 ? lv : 0.f) * (1.f / 256.f);
  float rs = 1.f / sqrtf(var + 1e-5f);
  if (half != 0) return;
  float4 g0 = ((const float4*)ln_g)[fl * 2], g1 = ((const float4*)ln_g)[fl * 2 + 1];
  float4 e0 = ((const float4*)ln_b)[fl * 2], e1 = ((const float4*)ln_b)[fl * 2 + 1];
  float r[8];
  r[0] = (z[0] - mu) * rs * g0.x + e0.x; r[1] = (z[1] - mu) * rs * g0.y + e0.y;
  r[2] = (z[2] - mu) * rs * g0.z + e0.z; r[3] = (z[3] - mu) * rs * g0.w + e0.w;
  r[4] = (z[4] - mu) * rs * g1.x + e1.x; r[5] = (z[5] - mu) * rs * g1.y + e1.y;
  r[6] = (z[6] - mu) * rs * g1.z + e1.z; r[7] = (z[7] - mu) * rs * g1.w + e1.w;
  cur[(size_t)wid * 32 + fl] = pack8h(r, SCL);
}

// ---------- launcher ----------
extern "C" void kernel_launch(void* const* d_in, const int* in_sizes, int n_in,
                              void* d_out, int out_size, void* d_ws, size_t ws_size,
                              hipStream_t stream) {
  const int*   he_node = (const int*)d_in[0];
  const int*   he_edge = (const int*)d_in[1];
  const float* stoich  = (const float*)d_in[2];
  const float* gene_x  = (const float*)d_in[3];
  const int*   rtg_rxn = (const int*)d_in[4];
  const int*   rtg_gene= (const int*)d_in[5];
  const float* emb     = (const float*)d_in[6];
  const float* W0      = (const float*)d_in[7];
  const float* We0     = (const float*)d_in[8];
  const float* att0    = (const float*)d_in[9];
  const float* b0      = (const float*)d_in[10];
  const float* W1      = (const float*)d_in[11];
  const float* We1     = (const float*)d_in[12];
  const float* att1    = (const float*)d_in[13];
  const float* b1      = (const float*)d_in[14];
  const float* ln_g    = (const float*)d_in[15];
  const float* ln_b    = (const float*)d_in[16];
  float* out = (float*)d_out;

  char* base = (char*)d_ws;
  size_t off = 0;
  auto carve = [&](size_t bytes) -> char* {
    char* p = base + off;
    off += (bytes + 255) & ~(size_t)255;
    return p;
  };
  __half* xp_h   = (__half*)carve((size_t)N_MET * DD * 2);
  __half* me_h   = (__half*)carve((size_t)N_RXN * DD * 2);
  __half* cur_h  = (__half*)carve((size_t)N_MET * DD * 2);
  __half* rxnf_h = (__half*)carve((size_t)N_RXN * DD * 2);
  float*  sn    = (float*)carve((size_t)N_MET * 4);
  float*  ve0   = (float*)carve(DD * 4);
  float*  ve1   = (float*)carve(DD * 4);
  float*  gdot0 = (float*)carve((size_t)N_GENE * 4);
  float*  gdot1 = (float*)carve((size_t)N_GENE * 4);
  float4* rstat = (float4*)carve((size_t)N_RXN * 16);
  int ztot = 3 * N_RXN;
  int* zbase = (int*)carve((size_t)ztot * 4);
  int*   cntR   = zbase;
  float* seAcc0 = (float*)(cntR + N_RXN);
  float* seAcc1 = seAcc0 + N_RXN;
  int*  offsE = (int*)carve((N_RXN + 1) * 4);
  int2* payE  = (int2*)carve((size_t)NE * 8);
  int*  offsN = (int*)carve((N_MET + 1) * 4);
  int2* payN  = (int2*)carve((size_t)NE * 8);
  int*  offsG = (int*)carve((N_GENE + 1) * 4);
  int*  rxnG  = (int*)carve((size_t)NP * 4);
  int2* scrE  = (int2*)carve((size_t)NE * 8);
  int2* scrN  = (int2*)carve((size_t)NE * 8);
  int*  scrG  = (int*)carve((size_t)NP * 4);
  int*  chE   = (int*)carve((size_t)NCHUNK * CHS * 4);
  int*  chN   = (int*)carve((size_t)NCHUNK * CHS * 4);
  int*  chG   = (int*)carve((size_t)NCHG * NBG * 4);
  int*  totE  = (int*)carve(128 * 4);
  int*  totN  = (int*)carve(128 * 4);
  int*  totG  = (int*)carve(128 * 4);

  hipMemsetAsync(zbase, 0, (size_t)ztot * 4, stream);

  // KH: vedot + LDS bucket hists (+ cntR atomics)
  KH_k<<<32 + NCHUNK, 1024, 0, stream>>>(
      he_node, he_edge, rtg_rxn, rtg_gene, cntR,
      chE, chN, chG, We0, att0, We1, att1, ve0, ve1);

  // KScan: column scans (emit per-bucket totals) + gdot
  int gdot_blocks = (N_GENE + 15) / 16;
  KScan_k<<<17 + gdot_blocks, 1024, 0, stream>>>(
      chE, chN, chG, totE, totN, totG, gene_x, ve0, ve1, gdot0, gdot1);

  // KP1: bucket partition (packed records, LDS cursors) + se atomics
  KP1_k<<<NCHUNK, 1024, 0, stream>>>(
      he_node, he_edge, stoich, chE, chN, chG, totE, totN, totG,
      scrE, scrN, scrG, rtg_rxn, rtg_gene, gdot0, gdot1, seAcc0, seAcc1);

  // KP2: in-bucket count/scan → offs arrays + CSR placement + gemm0 (xp fp16)
  KP2_k<<<KP2_GEMM0 + GEMM_BLOCKS, 256, 0, stream>>>(
      totE, totN, totG, scrE, scrN, scrG,
      offsE, offsN, offsG, payE, payN, rxnG,
      emb, W0, att0, xp_h, sn);

  // layer 0
  me_k<<<(N_RXN + 3) / 4, 256, 0, stream>>>(offsE, payE, sn, seAcc0, cntR,
                                            (const uint4*)xp_h, (uint4*)me_h, rstat);
  out_k<false><<<(N_MET + 3) / 4, 256, 0, stream>>>(offsN, payN, sn, rstat,
                                                    (const uint4*)me_h, b0,
                                                    nullptr, nullptr, (uint4*)cur_h);

  // layer 1
  gemm1_k<<<GEMM_BLOCKS, 256, 0, stream>>>(cur_h, W1, att1, xp_h, sn, N_MET);
  me_k<<<(N_RXN + 3) / 4, 256, 0, stream>>>(offsE, payE, sn, seAcc1, cntR,
                                            (const uint4*)xp_h, (uint4*)me_h, rstat);
  out_k<true><<<(N_MET + 3) / 4, 256, 0, stream>>>(offsN, payN, sn, rstat,
                                                   (const uint4*)me_h, b1,
                                                   ln_g, ln_b, (uint4*)cur_h);

  // final readout
  seg_mean_k<2, false><<<(N_RXN + 3) / 4, 256, 0, stream>>>(
      offsE, (const int*)payE, (const uint4*)cur_h, rxnf_h, N_RXN);
  seg_mean_k<1, true><<<(N_GENE + 3) / 4, 256, 0, stream>>>(
      offsG, rxnG, (const uint4*)rxnf_h, out, N_GENE);
}